// Round 10
// baseline (177.472 us; speedup 1.0000x reference)
//
#include <hip/hip_runtime.h>
#include <math.h>

// Problem constants
#define LQ 1024
#define EQ 512
#define BQ 32
#define MQ 64

static constexpr int BCHUNK = LQ * EQ;   // 524288 floats per b-slice of d_out
// d_out overlay (per b-slice of 524288 floats), phase by phase:
//  k_trig:   Tm bf16 A-frags in slice0 floats [0, 131072)
//  k_dft4:   reads q + Tm-frags; writes SPLITX bf16 arrays 0..3 (sx_ptr) in
//            slices z=0..7 at [z][262144, 524288)  (disjoint from Tm-frags)
//  k_modes8: Opart[hs][c][i] hs=0..3 at b*BCHUNK + hs*65536  [0,262144)
//  k_inv3:   y[l][i] overwrites slice. Each block reads ONLY its own i-columns
//            of the 4 partials (staged to LDS before any write -> WAR-safe).

typedef short short8 __attribute__((ext_vector_type(8)));
typedef float f32x4 __attribute__((ext_vector_type(4)));
typedef unsigned short ushort_t;

union FragI { int i[4]; int4 v; short8 s; };

// async global->LDS, 16B per lane; dest must be wave-uniform base (+lane*16 HW)
__device__ __forceinline__ void gload16(const float* g, float* l) {
    __builtin_amdgcn_global_load_lds(
        (const __attribute__((address_space(1))) void*)g,
        (__attribute__((address_space(3))) void*)l, 16, 0, 0);
}

// SPLITX: 4 bf16 arrays [m(64)][hblk(16)][b(32)][hh(32)], arr: 0=xrHi 1=xrLo
// 2=xiHi 3=xiLo. Flat bf16 index G = arr*2^20 + m*16384 + (h/32)*1024 + b*32
// + (h%32), mapped into 1MB-float zones: z = G>>19 at slice z offset 262144.
__device__ inline char* sx_ptr(float* dout, int arr, int m, int b, int h) {
    unsigned G = ((unsigned)arr << 20) + ((unsigned)m << 14) +
                 ((unsigned)(h >> 5) << 10) + ((unsigned)b << 5) + (unsigned)(h & 31);
    unsigned z = G >> 19, w = G & 524287u;
    return (char*)(dout + (size_t)z * BCHUNK + 262144) + (size_t)w * 2;
}

// split two fp32 into packed bf16 pairs (truncation; lo captures the residual)
__device__ inline void split2(float a, float b, unsigned& hi, unsigned& lo) {
    unsigned ua = __float_as_uint(a), ub = __float_as_uint(b);
    unsigned ha = ua & 0xFFFF0000u, hb = ub & 0xFFFF0000u;
    hi = (ua >> 16) | hb;
    float la = a - __uint_as_float(ha);
    float lb = b - __uint_as_float(hb);
    lo = (__float_as_uint(la) >> 16) | (__float_as_uint(lb) & 0xFFFF0000u);
}

__device__ inline void split1(float x, ushort_t& hi, ushort_t& lo) {
    unsigned u = __float_as_uint(x);
    hi = (ushort_t)(u >> 16);
    float r = x - __uint_as_float(u & 0xFFFF0000u);
    lo = (ushort_t)(__float_as_uint(r) >> 16);
}

// ---------------- kernel 0: trig tables (unchanged) ----------------
__global__ __launch_bounds__(256) void k_trig(unsigned* __restrict__ BFhi,
                                              unsigned* __restrict__ BFlo,
                                              float* __restrict__ dout) {
    int idx = blockIdx.x * 256 + threadIdx.x;   // 0..65535 = l*64+m
    int l = idx >> 6, m = idx & 63;
    int tt = (l * m) & (LQ - 1);
    float ang = (float)tt * 6.135923151542565e-03f;  // 2*pi/1024
    float s, c;
    sincosf(ang, &s, &c);
    float coef = (m == 0 ? 1.0f : 2.0f) * (1.0f / (float)LQ);
    float b0 = coef * c;
    float b1 = (m == 0) ? 0.0f : (-2.0f / (float)LQ) * s;
    unsigned hi, lo;
    split2(b0, b1, hi, lo);
    {
        int lt = l >> 4, kb = m >> 4, kgb = (m & 15) >> 2;
        int lane = kgb * 16 + (l & 15);
        int u = lt * 1024 + kb * 256 + lane * 4 + (m & 3);
        BFhi[u] = hi;
        BFlo[u] = lo;
    }
    ushort_t* THs = (ushort_t*)dout;
    ushort_t* TLs = (ushort_t*)(dout + 65536);
    int ks = l >> 5, kg = (l >> 3) & 3, j = l & 7;
    int mt = m >> 3;
    int lane0 = kg * 16 + 2 * (m & 7);
    ushort_t ch, cl, sh, sl;
    split1(c, ch, cl);
    split1(-s, sh, sl);
    int u0 = ((ks * 8 + mt) * 64 + lane0) * 8 + j;
    THs[u0] = ch;  TLs[u0] = cl;
    THs[u0 + 8] = sh;  TLs[u0 + 8] = sl;
}

#define MM(A, B, C) C = __builtin_amdgcn_mfma_f32_16x16x32_bf16(A, B, C, 0, 0, 0)

// ---------------- kernel 1: truncated DFT via MFMA (unchanged round-9) -----
__global__ __launch_bounds__(512, 4) void k_dft4(const float* __restrict__ q,
                                                 float* __restrict__ dout) {
    __shared__ float qs[2 * 2048];      // 16KB: [buf][lp 64][h 32]
    const int t    = threadIdx.x;
    const int wave = t >> 6;
    const int lane = t & 63;
    const int a    = wave & 3;
    const int ht   = wave >> 2;
    const int b    = blockIdx.x >> 4;
    const int hg   = blockIdx.x & 15;
    const int hbase = hg * 32;
    const int col  = lane & 15;
    const int kg   = lane >> 4;
    const float* qb = q + (size_t)b * BCHUNK;
    const int4* TH4 = (const int4*)dout;
    const int4* TL4 = (const int4*)(dout + 65536);

    f32x4 acc[2] = {{0.f, 0.f, 0.f, 0.f}, {0.f, 0.f, 0.f, 0.f}};
    const int lp = wave * 8 + (lane >> 3);     // slot row for gload src
    const int hq = 4 * (lane & 7);

    gload16(qb + (size_t)lp * EQ + hbase + hq, &qs[wave * 256]);

    int cur = 0;
    for (int cc = 0; cc < 16; ++cc) {
        __syncthreads();                        // q(cc) ready in buf[cur]
        FragI ah[2][2], al[2][2];
#pragma unroll
        for (int ksl = 0; ksl < 2; ++ksl)
#pragma unroll
            for (int ti = 0; ti < 2; ++ti) {
                int idx = ((cc * 2 + ksl) * 8 + 2 * a + ti) * 64 + lane;
                ah[ksl][ti].v = TH4[idx];
                al[ksl][ti].v = TL4[idx];
            }
        if (cc < 15)
            gload16(qb + (size_t)((cc + 1) * 64 + lp) * EQ + hbase + hq,
                    &qs[(cur ^ 1) * 2048 + wave * 256]);
#pragma unroll
        for (int ksl = 0; ksl < 2; ++ksl) {
            float v[8];
#pragma unroll
            for (int j = 0; j < 8; ++j)
                v[j] = qs[cur * 2048 + (ksl * 32 + kg * 8 + j) * 32 + ht * 16 + col];
            FragI bhiF, bloF;
#pragma unroll
            for (int k2 = 0; k2 < 4; ++k2) {
                unsigned h_, l_;
                split2(v[2 * k2], v[2 * k2 + 1], h_, l_);
                bhiF.i[k2] = (int)h_;
                bloF.i[k2] = (int)l_;
            }
#pragma unroll
            for (int ti = 0; ti < 2; ++ti) {
                MM(ah[ksl][ti].s, bhiF.s, acc[ti]);
                MM(ah[ksl][ti].s, bloF.s, acc[ti]);
                MM(al[ksl][ti].s, bhiF.s, acc[ti]);
            }
        }
        cur ^= 1;
    }
    const int h = hbase + ht * 16 + col;
#pragma unroll
    for (int ti = 0; ti < 2; ++ti) {
        int mt = 2 * a + ti;
        int mA = mt * 8 + kg * 2;
#pragma unroll
        for (int mi = 0; mi < 2; ++mi) {
            float xr = acc[ti][2 * mi];
            float xi = acc[ti][2 * mi + 1];
            ushort_t rh, rl, ih_, il_;
            split1(xr, rh, rl);
            split1(xi, ih_, il_);
            int m = mA + mi;
            *(ushort_t*)sx_ptr(dout, 0, m, b, h) = rh;
            *(ushort_t*)sx_ptr(dout, 1, m, b, h) = rl;
            *(ushort_t*)sx_ptr(dout, 2, m, b, h) = ih_;
            *(ushort_t*)sx_ptr(dout, 3, m, b, h) = il_;
        }
    }
}

// ---------------- kernel 2: per-mode complex GEMM, v9 ----------------
// Opart[hs][b][2m+ri][i] = sum_{h in hs quarter} X[b][h][m] * W[h][i][m]
// grid 512 = hs(4) x mg(16: 4 m) x it(8: 64 i). block 512 = 8 waves:
// isub=wave>>1 (16-i subtile), mw=wave&1 (m-pair). 2 blocks/CU, 16 waves.
// W LDS slot[part*32+h][i64][m4]: gload16 src naturally contiguous (no swz);
// READW = stride-4-float ds reads -> 2-way bank conflicts (free).
// Pipeline: READW->regs, barrier, STAGE(next chunk) overlaps LDX+MFMA,
// barrier drains. X re-read factor 8 (was 32); 16 mg-blocks per (hs,it)
// share W lines on one XCD (blk&7 = it).
__global__ __launch_bounds__(512, 4) void k_modes8(const float* __restrict__ wreal,
                                                   const float* __restrict__ wimag,
                                                   float* __restrict__ dout) {
    __shared__ float Wlds[16384];        // 64KB
    const int t    = threadIdx.x;
    const int wave = t >> 6;
    const int lane = t & 63;
    const int isub = wave >> 1;          // 0..3
    const int mw   = wave & 1;           // 0..1
    const int blk  = blockIdx.x;
    const int hs   = blk >> 7;           // 0..3
    const int mg   = (blk >> 3) & 15;    // 0..15
    const int it   = blk & 7;            // 0..7
    const int i0   = it * 64;
    const int m0   = mg * 4;
    const int col  = lane & 15;
    const int kg   = lane >> 4;
    const int hbase = hs * 128;

    const char* xp0 = sx_ptr(dout, 0, m0 + 2 * mw, col, hbase + kg * 8);

    f32x4 zero4 = {0.f, 0.f, 0.f, 0.f};
    f32x4 acc[2][2][2];                  // [mi][part][nt]
#pragma unroll
    for (int a = 0; a < 2; ++a)
#pragma unroll
        for (int bq = 0; bq < 2; ++bq)
#pragma unroll
            for (int c = 0; c < 2; ++c) acc[a][bq][c] = zero4;

    FragI xA[4], xB[4];
    short8 aW[2][2][2];                  // [mi][part][prec]

#define STAGE(KK)                                                             \
    {                                                                         \
        _Pragma("unroll")                                                     \
        for (int r = 0; r < 8; ++r) {                                         \
            const int W64_ = r * 8 + wave;                                    \
            const int part_ = W64_ >> 5;                                      \
            const int h_ = W64_ & 31;                                         \
            const float* src_ = (part_ ? wimag : wreal) +                     \
                (size_t)(hbase + (KK) * 32 + h_) * 32768 +                    \
                (size_t)(i0 + lane) * 64 + m0;                                \
            gload16(src_, &Wlds[W64_ * 256]);                                 \
        }                                                                     \
    }

#define LDX(BUF, MI, NT, KK)                                                  \
    {                                                                         \
        const char* xpm_ = xp0 + (size_t)(MI) * 32768 +                       \
                           (size_t)(KK) * 2048 + (size_t)(NT) * 1024;         \
        BUF[0].v = *(const int4*)(xpm_);                                      \
        BUF[1].v = *(const int4*)(xpm_ + 4194304);                            \
        BUF[2].v = *(const int4*)(xpm_ + 2 * 4194304);                        \
        BUF[3].v = *(const int4*)(xpm_ + 3 * 4194304);                        \
    }

#define MMG(MI, NT, BUF)                                                      \
    {                                                                         \
        FragI th_, tl_, nh_, nl_;                                             \
        th_.s = aW[MI][1][0]; tl_.s = aW[MI][1][1];                           \
        _Pragma("unroll")                                                     \
        for (int k2 = 0; k2 < 4; ++k2) {                                      \
            nh_.i[k2] = th_.i[k2] ^ 0x80008000;                               \
            nl_.i[k2] = tl_.i[k2] ^ 0x80008000;                               \
        }                                                                     \
        MM(aW[MI][0][0], BUF[0].s, acc[MI][0][NT]);                           \
        MM(aW[MI][0][0], BUF[1].s, acc[MI][0][NT]);                           \
        MM(aW[MI][0][1], BUF[0].s, acc[MI][0][NT]);                           \
        MM(nh_.s,        BUF[2].s, acc[MI][0][NT]);                           \
        MM(nh_.s,        BUF[3].s, acc[MI][0][NT]);                           \
        MM(nl_.s,        BUF[2].s, acc[MI][0][NT]);                           \
        MM(aW[MI][0][0], BUF[2].s, acc[MI][1][NT]);                           \
        MM(aW[MI][0][0], BUF[3].s, acc[MI][1][NT]);                           \
        MM(aW[MI][0][1], BUF[2].s, acc[MI][1][NT]);                           \
        MM(aW[MI][1][0], BUF[0].s, acc[MI][1][NT]);                           \
        MM(aW[MI][1][0], BUF[1].s, acc[MI][1][NT]);                           \
        MM(aW[MI][1][1], BUF[0].s, acc[MI][1][NT]);                           \
    }

    STAGE(0);
    LDX(xA, 0, 0, 0);
    __syncthreads();                     // chunk 0 resident in Wlds
    for (int kk = 0; kk < 4; ++kk) {
        // ---- READW all W-fragments for this chunk into registers ----
#pragma unroll
        for (int part = 0; part < 2; ++part) {
            float2 v2[8];
#pragma unroll
            for (int j = 0; j < 8; ++j)
                v2[j] = *(const float2*)&Wlds[(part * 32 + kg * 8 + j) * 256 +
                                              (isub * 16 + col) * 4 + 2 * mw];
#pragma unroll
            for (int mi = 0; mi < 2; ++mi) {
                FragI hiF, loF;
#pragma unroll
                for (int k2 = 0; k2 < 4; ++k2) {
                    float a_ = mi ? v2[2 * k2].y : v2[2 * k2].x;
                    float b_ = mi ? v2[2 * k2 + 1].y : v2[2 * k2 + 1].x;
                    unsigned h_, l_;
                    split2(a_, b_, h_, l_);
                    hiF.i[k2] = (int)h_;
                    loF.i[k2] = (int)l_;
                }
                aW[mi][part][0] = hiF.s;
                aW[mi][part][1] = loF.s;
            }
        }
        __syncthreads();                 // all waves done reading Wlds
        if (kk < 3) STAGE(kk + 1);       // prefetch next chunk (overlaps MFMA)
        LDX(xB, 0, 1, kk);
        MMG(0, 0, xA);
        LDX(xA, 1, 0, kk);
        MMG(0, 1, xB);
        LDX(xB, 1, 1, kk);
        MMG(1, 0, xA);
        if (kk < 3) LDX(xA, 0, 0, kk + 1);
        MMG(1, 1, xB);
        __syncthreads();                 // drains prefetch -> Wlds ready
    }
#undef STAGE
#undef LDX
#undef MMG
    // epilogue: D row = i = i0 + isub*16 + kg*4 + reg (contig float4), col = b
#pragma unroll
    for (int mi = 0; mi < 2; ++mi)
#pragma unroll
        for (int part = 0; part < 2; ++part)
#pragma unroll
            for (int nt = 0; nt < 2; ++nt) {
                int bb = nt * 16 + col;
                int c = 2 * (m0 + 2 * mw + mi) + part;
                f32x4 vv = acc[mi][part][nt];
                float4 o = make_float4(vv.x, vv.y, vv.z, vv.w);
                *(float4*)&dout[(size_t)bb * BCHUNK + (size_t)hs * 65536 +
                                (size_t)c * EQ + i0 + isub * 16 + kg * 4] = o;
            }
}

// ---------------- kernel 3: truncated irfft via MFMA (unchanged) ----------
__global__ __launch_bounds__(256) void k_inv3(const unsigned* __restrict__ BFhi,
                                              const unsigned* __restrict__ BFlo,
                                              float* __restrict__ dout) {
    __shared__ unsigned Bf[4096];   // [hilo(2)][nt(2)][kb(4)][lane(64)][4] 16KB
    const int t    = threadIdx.x;
    const int wave = t >> 6;
    const int lane = t & 63;
    const int b    = blockIdx.x >> 4;
    const int it   = blockIdx.x & 15;
    const int i0   = it * 32;
    float* base = dout + (size_t)b * BCHUNK;

#pragma unroll
    for (int r = 0; r < 8; ++r) {
        int idx = r * 256 + t;               // 2048 = 64 c-pairs x 32 i
        int il = idx & 31, cp = idx >> 5;
        int c0 = 2 * cp;
        const float* p0 = base + (size_t)c0 * EQ + i0 + il;
        float s0 = p0[0] + p0[65536] + p0[2 * 65536] + p0[3 * 65536];
        const float* p1 = p0 + EQ;
        float s1 = p1[0] + p1[65536] + p1[2 * 65536] + p1[3 * 65536];
        unsigned hi, lo;
        split2(s0, s1, hi, lo);
        int nt = il >> 4, i_loc = il & 15;
        int kb = c0 >> 5, kg = (c0 & 31) >> 3, jp = (c0 & 7) >> 1;
        int u = (nt * 4 + kb) * 256 + (kg * 16 + i_loc) * 4 + jp;
        Bf[u] = hi;
        Bf[2048 + u] = lo;
    }
    __syncthreads();
    FragI bh[2][4], bl[2][4];
#pragma unroll
    for (int nt = 0; nt < 2; ++nt)
#pragma unroll
        for (int kb = 0; kb < 4; ++kb) {
            bh[nt][kb].v = *(const int4*)&Bf[(nt * 4 + kb) * 256 + lane * 4];
            bl[nt][kb].v = *(const int4*)&Bf[2048 + (nt * 4 + kb) * 256 + lane * 4];
        }
    for (int r = 0; r < 16; ++r) {
        int lt = wave + 4 * r;
        FragI ah[4], al[4];
#pragma unroll
        for (int kb = 0; kb < 4; ++kb) {
            ah[kb].v = *(const int4*)&BFhi[lt * 1024 + kb * 256 + lane * 4];
            al[kb].v = *(const int4*)&BFlo[lt * 1024 + kb * 256 + lane * 4];
        }
        f32x4 a0 = {0.f, 0.f, 0.f, 0.f}, a1 = {0.f, 0.f, 0.f, 0.f};
#pragma unroll
        for (int kb = 0; kb < 4; ++kb) {
            MM(ah[kb].s, bh[0][kb].s, a0);
            MM(ah[kb].s, bl[0][kb].s, a0);
            MM(al[kb].s, bh[0][kb].s, a0);
            MM(ah[kb].s, bh[1][kb].s, a1);
            MM(ah[kb].s, bl[1][kb].s, a1);
            MM(al[kb].s, bh[1][kb].s, a1);
        }
        int lrow = lt * 16 + (lane >> 4) * 4;
        int icol = i0 + (lane & 15);
#pragma unroll
        for (int j = 0; j < 4; ++j) {
            base[(size_t)(lrow + j) * EQ + icol]      = a0[j];
            base[(size_t)(lrow + j) * EQ + icol + 16] = a1[j];
        }
    }
}
#undef MM

extern "C" void kernel_launch(void* const* d_in, const int* in_sizes, int n_in,
                              void* d_out, int out_size, void* d_ws, size_t ws_size,
                              hipStream_t stream) {
    const float* q  = (const float*)d_in[0];
    const float* wr = (const float*)d_in[1];
    const float* wi = (const float*)d_in[2];
    float* out = (float*)d_out;
    unsigned* BFhi = (unsigned*)d_ws;           // u32 [0, 65536)
    unsigned* BFlo = BFhi + 65536;              // u32 [65536, 131072)

    hipLaunchKernelGGL(k_trig,   dim3(256), dim3(256), 0, stream, BFhi, BFlo, out);
    hipLaunchKernelGGL(k_dft4,   dim3(512), dim3(512), 0, stream, q, out);
    hipLaunchKernelGGL(k_modes8, dim3(512), dim3(512), 0, stream, wr, wi, out);
    hipLaunchKernelGGL(k_inv3,   dim3(512), dim3(256), 0, stream, BFhi, BFlo, out);
}